// Round 4
// baseline (143.472 us; speedup 1.0000x reference)
//
#include <hip/hip_runtime.h>

typedef unsigned int  u32;
typedef unsigned short u16;

typedef __bf16 bf16x8 __attribute__((ext_vector_type(8)));
typedef float  floatx4 __attribute__((ext_vector_type(4)));

#define N_ROWS 256
#define IN_F   8192
#define OUT_F  8320
#define JDIM   128
#define KDIM   16
#define JK     2048

#define BN      64
#define KSLAB   512
#define NSLAB   16
#define WSTRIDE 520   // u16; 1040 B: keeps b128 frag reads 16B-aligned, <=2-way banks

__device__ __forceinline__ u16 f2bf(float f) {
    u32 u = __float_as_uint(f);
    return (u16)((u + 0x7fffu + ((u >> 16) & 1u)) >> 16);
}
__device__ __forceinline__ float bf2f(u16 h) { return __uint_as_float(((u32)h) << 16); }

// Kernel A: copy X into out[:, :8192], cvt X->bf16 into Xb, zero diversity region of out.
__global__ __launch_bounds__(256) void prep_kernel(const float* __restrict__ X,
                                                   float* __restrict__ out,
                                                   u16* __restrict__ Xb)
{
    int t = blockIdx.x * 256 + threadIdx.x;      // 0..524287, one float4 each
    float4 v = reinterpret_cast<const float4*>(X)[t];
    int row = t >> 11;
    int c4  = t & 2047;
    reinterpret_cast<float4*>(out + (size_t)row * OUT_F)[c4] = v;
    ushort4 b;
    b.x = f2bf(v.x); b.y = f2bf(v.y); b.z = f2bf(v.z); b.w = f2bf(v.w);
    reinterpret_cast<ushort4*>(Xb)[t] = b;
    if (t < 8192) {
        int r2 = t >> 5, j4 = t & 31;
        reinterpret_cast<float4*>(out + (size_t)r2 * OUT_F + IN_F)[j4] = make_float4(0.f, 0.f, 0.f, 0.f);
    }
}

// Kernel B: slab[s] = Xb[256, kslab] * W[kslab, 64 cols].
// W-slab (512k x 64c bf16, 65KB) staged to LDS ONCE (the HBM-bound phase, 2-deep pipeline),
// one barrier, then a barrier-free MFMA loop: A-frags stream from global Xb (L2-resident),
// B-frags from LDS. Grid (32 col-blocks, 16 slabs) = 512 blocks, 2/CU.
__global__ __launch_bounds__(256) void gemm_kernel(const u16* __restrict__ Xb,
                                                   const float* __restrict__ W,
                                                   u16* __restrict__ slabs)
{
    __shared__ u16 wt[BN * WSTRIDE];    // 65 KB, [col][k]

    const int tid  = threadIdx.x;
    const int lane = tid & 63;
    const int wave = tid >> 6;
    const int c0   = blockIdx.x * BN;
    const int s    = blockIdx.y;
    const int k0   = s * KSLAB;

    // ---- stage W: 8 passes of 64 k-rows; per pass/thread 4x dwordx4 (4 cols x 4 k) ----
    {
        const int wc4 = (tid & 15) << 2;         // col group: 0,4,...,60
        const int wk4 = (tid >> 4) << 2;         // k within 64-row pass: 0,4,...,60
        const float* wp0 = W + (size_t)(k0 + wk4) * JK + c0 + wc4;

        float4 wr[2][4];
        #pragma unroll
        for (int r = 0; r < 4; ++r) wr[0][r] = *(const float4*)(wp0 + (size_t)r * JK);
        #pragma unroll
        for (int r = 0; r < 4; ++r) wr[1][r] = *(const float4*)(wp0 + (size_t)(64 + r) * JK);

        #pragma unroll
        for (int p = 0; p < 8; ++p) {
            // pack pass p from wr[p&1]; prefetch pass p+2
            float4* cur = wr[p & 1];
            u32 pk[4][2];
            #pragma unroll
            for (int i = 0; i < 4; ++i) {
                const float* c = (const float*)cur;   // [r][i]
                pk[i][0] = (u32)f2bf(c[0 * 4 + i]) | ((u32)f2bf(c[1 * 4 + i]) << 16);
                pk[i][1] = (u32)f2bf(c[2 * 4 + i]) | ((u32)f2bf(c[3 * 4 + i]) << 16);
            }
            if (p + 2 < 8) {
                const float* wn = wp0 + (size_t)(p + 2) * 64 * JK;
                #pragma unroll
                for (int r = 0; r < 4; ++r) cur[r] = *(const float4*)(wn + (size_t)r * JK);
            }
            #pragma unroll
            for (int i = 0; i < 4; ++i)
                *(uint2*)&wt[(wc4 + i) * WSTRIDE + p * 64 + wk4] = *(uint2*)pk[i];
        }
    }
    __syncthreads();    // the ONLY barrier

    // ---- barrier-free main loop: 16 k-iters of 32k ----
    const int mrow = lane & 15;
    const int q    = lane >> 4;

    floatx4 acc[4][4] = {};             // wave owns rows wave*64..+63, all 64 cols

    const u16* arow[4];
    #pragma unroll
    for (int rt = 0; rt < 4; ++rt)
        arow[rt] = Xb + (size_t)(wave * 64 + rt * 16 + mrow) * IN_F + k0 + q * 8;

    bf16x8 a[4], an[4];
    #pragma unroll
    for (int rt = 0; rt < 4; ++rt) a[rt] = *(const bf16x8*)(arow[rt]);

    for (int kc = 0; kc < 16; ++kc) {
        // prefetch next A-frags (global, L2-resident) before consuming current
        if (kc + 1 < 16) {
            #pragma unroll
            for (int rt = 0; rt < 4; ++rt)
                an[rt] = *(const bf16x8*)(arow[rt] + (kc + 1) * 32);
        }
        bf16x8 b[4];
        #pragma unroll
        for (int ct = 0; ct < 4; ++ct) {
            int col = ct * 16 + mrow;
            b[ct] = *(const bf16x8*)(&wt[col * WSTRIDE + kc * 32 + q * 8]);
        }
        #pragma unroll
        for (int rt = 0; rt < 4; ++rt)
            #pragma unroll
            for (int ct = 0; ct < 4; ++ct)
                acc[rt][ct] = __builtin_amdgcn_mfma_f32_16x16x32_bf16(a[rt], b[ct], acc[rt][ct], 0, 0, 0);
        #pragma unroll
        for (int rt = 0; rt < 4; ++rt) a[rt] = an[rt];
    }

    // ---- epilogue: bf16 stores. D: col=lane&15, row=(lane>>4)*4+reg ----
    const int qe = lane >> 4;
    const int cl = lane & 15;
    u16* sp = slabs + (size_t)s * N_ROWS * JK;
    #pragma unroll
    for (int rt = 0; rt < 4; ++rt)
        #pragma unroll
        for (int ct = 0; ct < 4; ++ct)
            #pragma unroll
            for (int r = 0; r < 4; ++r) {
                int row = wave * 64 + rt * 16 + qe * 4 + r;
                int col = c0 + ct * 16 + cl;
                sp[(size_t)row * JK + col] = f2bf(acc[rt][ct][r]);
            }
}

// Kernel C: feats[n,jk] = sum_s slab[s][n,jk] (bf16 -> fp32).
__global__ __launch_bounds__(256) void reduce_kernel(const u16* __restrict__ slabs,
                                                     float* __restrict__ feats)
{
    int t = blockIdx.x * 256 + threadIdx.x;      // 65536 threads x 8 elems
    float acc[8] = {};
    for (int s = 0; s < NSLAB; ++s) {
        uint4 v = *(const uint4*)(slabs + (size_t)s * N_ROWS * JK + (size_t)t * 8);
        const u16* h = (const u16*)&v;
        #pragma unroll
        for (int e = 0; e < 8; ++e) acc[e] += bf2f(h[e]);
    }
    float4* fp = (float4*)(feats + (size_t)t * 8);
    fp[0] = make_float4(acc[0], acc[1], acc[2], acc[3]);
    fp[1] = make_float4(acc[4], acc[5], acc[6], acc[7]);
}

// Kernel D: diversity[n,j] = sum_m exp(-sum_k |feats[n,j,k]-feats[m,j,k]|), m-chunked.
__global__ __launch_bounds__(256) void pairwise_kernel(const float* __restrict__ feats,
                                                       float* __restrict__ out)
{
    const int j = blockIdx.x;              // 0..127
    const int mq = blockIdx.y;             // 0..3 -> m chunk of 64
    const int n = threadIdx.x;

    __shared__ float F[N_ROWS * KDIM];     // 16 KB
    const float* fr = feats + (size_t)n * JK + j * KDIM;
    float4 v0 = ((const float4*)fr)[0];
    float4 v1 = ((const float4*)fr)[1];
    float4 v2 = ((const float4*)fr)[2];
    float4 v3 = ((const float4*)fr)[3];
    float4* Fp = (float4*)&F[n * KDIM];
    Fp[0] = v0; Fp[1] = v1; Fp[2] = v2; Fp[3] = v3;
    __syncthreads();

    float f[16] = { v0.x, v0.y, v0.z, v0.w, v1.x, v1.y, v1.z, v1.w,
                    v2.x, v2.y, v2.z, v2.w, v3.x, v3.y, v3.z, v3.w };
    float accum = 0.f;
    const int m0 = mq * 64;
    for (int m = 0; m < 64; ++m) {
        const float* Fm = &F[(m0 + m) * KDIM];   // wave-uniform -> LDS broadcast
        float l1 = 0.f;
        #pragma unroll
        for (int k = 0; k < 16; ++k) l1 += fabsf(f[k] - Fm[k]);
        accum += exp2f(-1.4426950408889634f * l1);
    }
    atomicAdd(&out[(size_t)n * OUT_F + IN_F + j], accum);
}

extern "C" void kernel_launch(void* const* d_in, const int* in_sizes, int n_in,
                              void* d_out, int out_size, void* d_ws, size_t ws_size,
                              hipStream_t stream)
{
    const float* X = (const float*)d_in[0];   // [256, 8192] fp32
    const float* T = (const float*)d_in[1];   // [8192, 128, 16] fp32 = [8192, 2048]
    float* out = (float*)d_out;               // [256, 8320] fp32

    float* feats = (float*)d_ws;                            // 2 MB fp32 [256,2048]
    u16*   Xb    = (u16*)((char*)d_ws + (2u << 20));        // 4 MB bf16 [256,8192]
    u16*   slabs = (u16*)((char*)d_ws + (6u << 20));        // 16 MB bf16 [16,256,2048]

    prep_kernel<<<2048, 256, 0, stream>>>(X, out, Xb);
    gemm_kernel<<<dim3(JK / BN, NSLAB), 256, 0, stream>>>(Xb, T, slabs);
    reduce_kernel<<<256, 256, 0, stream>>>(slabs, feats);
    pairwise_kernel<<<dim3(JDIM, 4), 256, 0, stream>>>(feats, out);
}